// Round 6
// baseline (240.390 us; speedup 1.0000x reference)
//
#include <hip/hip_runtime.h>
#include <hip/hip_bf16.h>
#include <math.h>

#define IN_DIM 128
#define OUT_DIM 128
#define BM 64

#define BSHIFT 9            // nodes per coarse bucket = 512
#define BNODES 512
#define CAP 12288           // pair capacity per coarse bucket region
#define EPT 16              // edges per thread in coarse_scatter

typedef short bf16x8s __attribute__((ext_vector_type(8)));
typedef float f32x4 __attribute__((ext_vector_type(4)));
typedef unsigned short u16;
typedef unsigned short u16x8 __attribute__((ext_vector_type(8)));
typedef unsigned int u32x2 __attribute__((ext_vector_type(2)));

__device__ inline unsigned int rne_hi(float f) {
    unsigned int u = __float_as_uint(f);
    return u + 0x7fffu + ((u >> 16) & 1u);   // high 16 bits = RNE bf16
}
__device__ inline unsigned int pack_bf16x2(float lo, float hi) {
    return (rne_hi(lo) >> 16) | (rne_hi(hi) & 0xffff0000u);
}
__device__ inline float bf2f(u16 v) { return __uint_as_float(((unsigned)v) << 16); }

// ---------------------------------------------------------------------------
// K0: transpose + convert W [k][c] fp32 -> Wt bf16 [c][k]; also inits the
// coarse-bucket cursors (fused to save a launch).
// ---------------------------------------------------------------------------
__global__ void wt_kernel(const float* __restrict__ W, u16* __restrict__ Wt,
                          int* __restrict__ coarse_cur, int nbc)
{
    int k = blockIdx.x;
    int c = threadIdx.x;
    int ii = k * OUT_DIM + c;
    if (ii < nbc) coarse_cur[ii] = ii * CAP;
    float v = W[ii];
    Wt[c * IN_DIM + k] = (u16)(rne_hi(v) >> 16);
}

// ---------------------------------------------------------------------------
// K1: x = input @ W via bf16 MFMA; writes x as bf16; fused s_src/s_dst.
// input loaded non-temporally (use-once stream; keep L3 for xbf).
// ---------------------------------------------------------------------------
__global__ __launch_bounds__(256) void gemm_xw_kernel(
    const float* __restrict__ in, const u16* __restrict__ WtG,
    const float* __restrict__ a, u16* __restrict__ xbf,
    float* __restrict__ ssrc, float* __restrict__ sdst, int N)
{
    __shared__ u16 Al[BM][IN_DIM + 8];
    __shared__ u16 Wl[OUT_DIM][IN_DIM + 8];

    const int tid  = threadIdx.x;
    const int lane = tid & 63;
    const int wave = tid >> 6;
    const int rl   = lane & 15;
    const int rgrp = lane >> 4;

    {
        int r = tid >> 1, c0 = (tid & 1) * 64;
        const uint4* src = (const uint4*)(WtG + r * IN_DIM + c0);
        uint4* dst = (uint4*)&Wl[r][c0];
#pragma unroll
        for (int u = 0; u < 8; u++) dst[u] = src[u];
    }
    const long long rowbase = (long long)blockIdx.x * BM;
    {
#pragma unroll
        for (int u = 0; u < 8; u++) {
            int idx = u * 256 + tid;
            int r = idx >> 5;
            int c = (idx & 31) * 4;
            long long gr = rowbase + r;
            if (gr >= N) gr = N - 1;
            f32x4 v = __builtin_nontemporal_load((const f32x4*)(in + gr * IN_DIM + c));
            *(uint2*)&Al[r][c] = make_uint2(pack_bf16x2(v[0], v[1]), pack_bf16x2(v[2], v[3]));
        }
    }
    __syncthreads();

    f32x4 acc[8] = {};
#pragma unroll
    for (int ks = 0; ks < 4; ks++) {
        bf16x8s af = *(const bf16x8s*)&Al[wave * 16 + rl][ks * 32 + rgrp * 8];
#pragma unroll
        for (int cb = 0; cb < 8; cb++) {
            bf16x8s bf = *(const bf16x8s*)&Wl[cb * 16 + rl][ks * 32 + rgrp * 8];
            acc[cb] = __builtin_amdgcn_mfma_f32_16x16x32_bf16(af, bf, acc[cb], 0, 0, 0);
        }
    }

    float a_sv[8], a_dv[8];
#pragma unroll
    for (int cb = 0; cb < 8; cb++) {
        a_sv[cb] = a[rl + 16 * cb];
        a_dv[cb] = a[OUT_DIM + rl + 16 * cb];
    }
#pragma unroll
    for (int r = 0; r < 4; r++) {
        long long grow = rowbase + wave * 16 + rgrp * 4 + r;
        float ps = 0.f, pd = 0.f;
#pragma unroll
        for (int cb = 0; cb < 8; cb++) {
            float v = acc[cb][r];
            if (grow < N) xbf[grow * OUT_DIM + rl + 16 * cb] = (u16)(rne_hi(v) >> 16);
            ps += v * a_sv[cb];
            pd += v * a_dv[cb];
        }
#pragma unroll
        for (int off = 1; off < 16; off <<= 1) {
            ps += __shfl_xor(ps, off);
            pd += __shfl_xor(pd, off);
        }
        if (rl == 0 && grow < N) { ssrc[grow] = ps; sdst[grow] = pd; }
    }
}

// ---------------------------------------------------------------------------
// K2: coarse scatter. Block handles 4096 edges: LDS histogram over coarse
// buckets (h>>9), one global atomic reserve per bucket, clustered pair writes.
// triple: nt loads; pairs: nt stores (both use-once streams).
// ---------------------------------------------------------------------------
__global__ __launch_bounds__(256) void coarse_scatter_kernel(
    const int* __restrict__ triple, int* __restrict__ coarse_cur,
    u32x2* __restrict__ pairs, int E, int nbc)
{
    __shared__ int cnt[256];
    __shared__ int base[256];
    const int tid = threadIdx.x;
    const int cbase = blockIdx.x * (256 * EPT);

    cnt[tid] = 0;
    __syncthreads();

    int h[EPT], t[EPT], pos[EPT];
#pragma unroll
    for (int it = 0; it < EPT; ++it) {
        int idx = cbase + it * 256 + tid;
        if (idx < E) {
            h[it] = __builtin_nontemporal_load(triple + 3 * idx);
            t[it] = __builtin_nontemporal_load(triple + 3 * idx + 2);
            pos[it] = atomicAdd(&cnt[h[it] >> BSHIFT], 1);
        }
    }
    __syncthreads();
    if (tid < nbc && cnt[tid] > 0) base[tid] = atomicAdd(&coarse_cur[tid], cnt[tid]);
    __syncthreads();
#pragma unroll
    for (int it = 0; it < EPT; ++it) {
        int idx = cbase + it * 256 + tid;
        if (idx < E) {
            u32x2 pr;
            pr[0] = (unsigned)h[it];
            pr[1] = (unsigned)t[it];
            __builtin_nontemporal_store(pr, &pairs[base[h[it] >> BSHIFT] + pos[it]]);
        }
    }
}

// ---------------------------------------------------------------------------
// K3: scan of bucket sizes -> dense CSR bucket bases (single block, nbc<=256)
// ---------------------------------------------------------------------------
__global__ __launch_bounds__(256) void bucket_scan_kernel(
    const int* __restrict__ coarse_cur, int* __restrict__ bstart, int nbc)
{
    __shared__ int s[256];
    int tid = threadIdx.x;
    int sz = (tid < nbc) ? (coarse_cur[tid] - tid * CAP) : 0;
    s[tid] = sz;
    __syncthreads();
#pragma unroll
    for (int off = 1; off < 256; off <<= 1) {
        int v = (tid >= off) ? s[tid - off] : 0;
        __syncthreads();
        s[tid] += v;
        __syncthreads();
    }
    if (tid < nbc) bstart[tid] = s[tid] - sz;
}

// ---------------------------------------------------------------------------
// K4: per-bucket CSR build. One block per coarse bucket: LDS histogram of its
// 512 nodes, LDS scan -> startp, LDS-cursor scatter of t into a local dense
// CSR window. pairs: nt loads; edge_t: nt stores.
// ---------------------------------------------------------------------------
__global__ __launch_bounds__(512) void bucket_csr_kernel(
    const u32x2* __restrict__ pairs, const int* __restrict__ coarse_cur,
    const int* __restrict__ bstart, int* __restrict__ startp,
    int* __restrict__ edge_t, int N, int E)
{
    __shared__ int cnt[BNODES];
    __shared__ int scn[BNODES];
    __shared__ int cursor[BNODES];
    const int b = blockIdx.x;
    const int tid = threadIdx.x;
    const int plo = b * CAP;
    const int psz = coarse_cur[b] - plo;
    const int obase = bstart[b];

    cnt[tid] = 0;
    __syncthreads();
    for (int j = tid; j < psz; j += BNODES) {
        u32x2 p = __builtin_nontemporal_load(&pairs[plo + j]);
        atomicAdd(&cnt[p[0] & (BNODES - 1)], 1);
    }
    __syncthreads();
    scn[tid] = cnt[tid];
    __syncthreads();
#pragma unroll
    for (int off = 1; off < BNODES; off <<= 1) {
        int v = (tid >= off) ? scn[tid - off] : 0;
        __syncthreads();
        scn[tid] += v;
        __syncthreads();
    }
    const int excl = scn[tid] - cnt[tid];
    const int node = b * BNODES + tid;
    if (node < N) startp[node] = obase + excl;
    cursor[tid] = obase + excl;
    __syncthreads();
    for (int j = tid; j < psz; j += BNODES) {
        u32x2 p = __builtin_nontemporal_load(&pairs[plo + j]);
        int pos = atomicAdd(&cursor[p[0] & (BNODES - 1)], 1);
        __builtin_nontemporal_store((int)p[1], &edge_t[pos]);
    }
    if (b == 0 && tid == 0) startp[N] = E;
}

// ---------------------------------------------------------------------------
// K5: per-node softmax aggregation. One wave/node. 8 edge-groups x 8 lanes;
// lane (k = lane>>3) owns dims [16k,16k+16). Scores computed in-register
// (deg<=64 fast path). bf16 x gather (cached — L3-resident). out: nt stores.
// ---------------------------------------------------------------------------
__global__ __launch_bounds__(256) void aggregate_kernel(
    const u16* __restrict__ xbf, const float* __restrict__ ssrc,
    const float* __restrict__ sdst, const int* __restrict__ startp,
    const int* __restrict__ edge_t, float* __restrict__ out, int N)
{
    const int wave = threadIdx.x >> 6;
    const int lane = threadIdx.x & 63;
    const int i = blockIdx.x * 4 + wave;
    if (i >= N) return;
    const int lo = startp[i];
    const int hi = startp[i + 1];
    const int deg = hi - lo;
    const float si = ssrc[i];
    const int k = lane >> 3;   // dim-slice 0..7
    const int g = lane & 7;    // edge-group 0..7

    float acc[16];
#pragma unroll
    for (int d = 0; d < 16; d++) acc[d] = 0.f;

    if (deg <= 64) {
        int j = lo + lane;
        bool act = j < hi;
        int t = act ? __builtin_nontemporal_load(edge_t + j) : 0;
        float e = act ? si + sdst[t] : -INFINITY;
        e = (e > 0.f) ? e : 0.2f * e;
        float m = e;
#pragma unroll
        for (int off = 32; off; off >>= 1) m = fmaxf(m, __shfl_xor(m, off));
        float p = act ? __expf(e - m) : 0.f;
        float den = p;
#pragma unroll
        for (int off = 32; off; off >>= 1) den += __shfl_xor(den, off);
        float w = (deg > 0) ? p / den : 0.f;

        int nit = (deg + 7) >> 3;
        for (int it = 0; it < nit; ++it) {
            int ei = it * 8 + g;
            int tt = __shfl(t, ei);
            float ww = __shfl(w, ei);
            if (ei < deg) {
                const u16x8* src = (const u16x8*)(xbf + (size_t)tt * OUT_DIM + k * 16);
                u16x8 v0 = src[0], v1 = src[1];
#pragma unroll
                for (int d = 0; d < 8; d++) {
                    acc[d]     += ww * bf2f(v0[d]);
                    acc[8 + d] += ww * bf2f(v1[d]);
                }
            }
        }
    } else {
        float m = -INFINITY;
        for (int j = lo + lane; j < hi; j += 64) {
            int t = edge_t[j];
            float e = si + sdst[t];
            e = (e > 0.f) ? e : 0.2f * e;
            m = fmaxf(m, e);
        }
#pragma unroll
        for (int off = 32; off; off >>= 1) m = fmaxf(m, __shfl_xor(m, off));
        float den = 0.f;
        for (int j = lo + lane; j < hi; j += 64) {
            int t = edge_t[j];
            float e = si + sdst[t];
            e = (e > 0.f) ? e : 0.2f * e;
            den += __expf(e - m);
        }
#pragma unroll
        for (int off = 32; off; off >>= 1) den += __shfl_xor(den, off);
        const float invden = 1.f / den;

        for (int jj = lo; jj < hi; jj += 8) {
            int ei = jj + g;
            if (ei < hi) {
                int tt = edge_t[ei];
                float e = si + sdst[tt];
                e = (e > 0.f) ? e : 0.2f * e;
                float ww = __expf(e - m) * invden;
                const u16x8* src = (const u16x8*)(xbf + (size_t)tt * OUT_DIM + k * 16);
                u16x8 v0 = src[0], v1 = src[1];
#pragma unroll
                for (int d = 0; d < 8; d++) {
                    acc[d]     += ww * bf2f(v0[d]);
                    acc[8 + d] += ww * bf2f(v1[d]);
                }
            }
        }
    }

#pragma unroll
    for (int off = 1; off < 8; off <<= 1) {
#pragma unroll
        for (int d = 0; d < 16; d++) acc[d] += __shfl_xor(acc[d], off);
    }

    if (g == 0) {
        const u16x8* xr = (const u16x8*)(xbf + (size_t)i * OUT_DIM + k * 16);
        u16x8 x0 = xr[0], x1 = xr[1];
        float o[16];
#pragma unroll
        for (int d = 0; d < 8; d++) {
            o[d]     = acc[d]     + bf2f(x0[d]);
            o[8 + d] = acc[8 + d] + bf2f(x1[d]);
        }
#pragma unroll
        for (int d = 0; d < 16; d++) o[d] = (o[d] > 0.f) ? o[d] : __expf(o[d]) - 1.f;
        float* dst = out + (size_t)i * OUT_DIM + k * 16;
#pragma unroll
        for (int u = 0; u < 4; u++) {
            f32x4 ov;
            ov[0] = o[u*4]; ov[1] = o[u*4+1]; ov[2] = o[u*4+2]; ov[3] = o[u*4+3];
            __builtin_nontemporal_store(ov, (f32x4*)(dst + u * 4));
        }
    }
}

// ---------------------------------------------------------------------------
extern "C" void kernel_launch(void* const* d_in, const int* in_sizes, int n_in,
                              void* d_out, int out_size, void* d_ws, size_t ws_size,
                              hipStream_t stream)
{
    const float* input  = (const float*)d_in[0];
    const float* W      = (const float*)d_in[1];
    const float* a      = (const float*)d_in[2];
    const int*   triple = (const int*)d_in[3];
    const int N = in_sizes[0] / IN_DIM;
    const int E = in_sizes[3] / 3;
    float* out = (float*)d_out;

    const int NBC = (N + BNODES - 1) >> BSHIFT;   // coarse buckets (<=256)

    // workspace layout
    char* p = (char*)d_ws;
    u16* xbf = (u16*)p;                 p += (size_t)N * OUT_DIM * sizeof(u16);
    u16* Wt  = (u16*)p;                 p += (size_t)IN_DIM * OUT_DIM * sizeof(u16);
    float* ssrc = (float*)p;            p += (size_t)N * sizeof(float);
    float* sdst = (float*)p;            p += (size_t)N * sizeof(float);
    int* startp = (int*)p;              p += (size_t)(N + 1) * sizeof(int);
    int* coarse_cur = (int*)p;          p += 256 * sizeof(int);
    int* bstart = (int*)p;              p += 256 * sizeof(int);
    int* edge_t = (int*)p;              p += (size_t)E * sizeof(int);
    p = (char*)(((size_t)p + 15) & ~(size_t)15);
    u32x2* pairs = (u32x2*)p;           // NBC * CAP * 8 bytes

    const int NCHUNK = (E + 256 * EPT - 1) / (256 * EPT);

    wt_kernel<<<IN_DIM, OUT_DIM, 0, stream>>>(W, Wt, coarse_cur, NBC);
    gemm_xw_kernel<<<(N + BM - 1) / BM, 256, 0, stream>>>(input, Wt, a, xbf, ssrc, sdst, N);
    coarse_scatter_kernel<<<NCHUNK, 256, 0, stream>>>(triple, coarse_cur, pairs, E, NBC);
    bucket_scan_kernel<<<1, 256, 0, stream>>>(coarse_cur, bstart, NBC);
    bucket_csr_kernel<<<NBC, BNODES, 0, stream>>>(pairs, coarse_cur, bstart, startp, edge_t, N, E);
    aggregate_kernel<<<(N + 3) / 4, 256, 0, stream>>>(xbf, ssrc, sdst, startp, edge_t, out, N);
}

// Round 7
// 189.543 us; speedup vs baseline: 1.2683x; 1.2683x over previous
//
#include <hip/hip_runtime.h>
#include <hip/hip_bf16.h>
#include <math.h>

#define IN_DIM 128
#define OUT_DIM 128
#define BM 64

#define BSHIFT 9            // nodes per coarse bucket = 512
#define BNODES 512
#define CAP 12288           // pair capacity per coarse bucket region
#define EPT 16              // edges per thread in coarse_scatter

typedef short bf16x8s __attribute__((ext_vector_type(8)));
typedef float f32x4 __attribute__((ext_vector_type(4)));
typedef unsigned short u16;
typedef unsigned short u16x8 __attribute__((ext_vector_type(8)));

__device__ inline unsigned int rne_hi(float f) {
    unsigned int u = __float_as_uint(f);
    return u + 0x7fffu + ((u >> 16) & 1u);   // high 16 bits = RNE bf16
}
__device__ inline unsigned int pack_bf16x2(float lo, float hi) {
    return (rne_hi(lo) >> 16) | (rne_hi(hi) & 0xffff0000u);
}
__device__ inline float bf2f(u16 v) { return __uint_as_float(((unsigned)v) << 16); }

// ---------------------------------------------------------------------------
// K0: transpose + convert W [k][c] fp32 -> Wt bf16 [c][k]; also inits the
// coarse-bucket cursors (fused to save a launch).
// ---------------------------------------------------------------------------
__global__ void wt_kernel(const float* __restrict__ W, u16* __restrict__ Wt,
                          int* __restrict__ coarse_cur, int nbc)
{
    int k = blockIdx.x;
    int c = threadIdx.x;
    int ii = k * OUT_DIM + c;
    if (ii < nbc) coarse_cur[ii] = ii * CAP;
    float v = W[ii];
    Wt[c * IN_DIM + k] = (u16)(rne_hi(v) >> 16);
}

// ---------------------------------------------------------------------------
// K1: x = input @ W via bf16 MFMA; writes x as bf16; fused s_src/s_dst.
// ---------------------------------------------------------------------------
__global__ __launch_bounds__(256) void gemm_xw_kernel(
    const float* __restrict__ in, const u16* __restrict__ WtG,
    const float* __restrict__ a, u16* __restrict__ xbf,
    float* __restrict__ ssrc, float* __restrict__ sdst, int N)
{
    __shared__ u16 Al[BM][IN_DIM + 8];
    __shared__ u16 Wl[OUT_DIM][IN_DIM + 8];

    const int tid  = threadIdx.x;
    const int lane = tid & 63;
    const int wave = tid >> 6;
    const int rl   = lane & 15;
    const int rgrp = lane >> 4;

    {
        int r = tid >> 1, c0 = (tid & 1) * 64;
        const uint4* src = (const uint4*)(WtG + r * IN_DIM + c0);
        uint4* dst = (uint4*)&Wl[r][c0];
#pragma unroll
        for (int u = 0; u < 8; u++) dst[u] = src[u];
    }
    const long long rowbase = (long long)blockIdx.x * BM;
    {
#pragma unroll
        for (int u = 0; u < 8; u++) {
            int idx = u * 256 + tid;
            int r = idx >> 5;
            int c = (idx & 31) * 4;
            long long gr = rowbase + r;
            if (gr >= N) gr = N - 1;
            float4 v = *(const float4*)(in + gr * IN_DIM + c);
            *(uint2*)&Al[r][c] = make_uint2(pack_bf16x2(v.x, v.y), pack_bf16x2(v.z, v.w));
        }
    }
    __syncthreads();

    f32x4 acc[8] = {};
#pragma unroll
    for (int ks = 0; ks < 4; ks++) {
        bf16x8s af = *(const bf16x8s*)&Al[wave * 16 + rl][ks * 32 + rgrp * 8];
#pragma unroll
        for (int cb = 0; cb < 8; cb++) {
            bf16x8s bf = *(const bf16x8s*)&Wl[cb * 16 + rl][ks * 32 + rgrp * 8];
            acc[cb] = __builtin_amdgcn_mfma_f32_16x16x32_bf16(af, bf, acc[cb], 0, 0, 0);
        }
    }

    float a_sv[8], a_dv[8];
#pragma unroll
    for (int cb = 0; cb < 8; cb++) {
        a_sv[cb] = a[rl + 16 * cb];
        a_dv[cb] = a[OUT_DIM + rl + 16 * cb];
    }
#pragma unroll
    for (int r = 0; r < 4; r++) {
        long long grow = rowbase + wave * 16 + rgrp * 4 + r;
        float ps = 0.f, pd = 0.f;
#pragma unroll
        for (int cb = 0; cb < 8; cb++) {
            float v = acc[cb][r];
            if (grow < N) xbf[grow * OUT_DIM + rl + 16 * cb] = (u16)(rne_hi(v) >> 16);
            ps += v * a_sv[cb];
            pd += v * a_dv[cb];
        }
#pragma unroll
        for (int off = 1; off < 16; off <<= 1) {
            ps += __shfl_xor(ps, off);
            pd += __shfl_xor(pd, off);
        }
        if (rl == 0 && grow < N) { ssrc[grow] = ps; sdst[grow] = pd; }
    }
}

// ---------------------------------------------------------------------------
// K2: coarse scatter. Block handles 4096 edges: LDS histogram over coarse
// buckets (h>>9), one global atomic reserve per bucket, clustered pair writes.
// ---------------------------------------------------------------------------
__global__ __launch_bounds__(256) void coarse_scatter_kernel(
    const int* __restrict__ triple, int* __restrict__ coarse_cur,
    uint2* __restrict__ pairs, int E, int nbc)
{
    __shared__ int cnt[256];
    __shared__ int base[256];
    const int tid = threadIdx.x;
    const int cbase = blockIdx.x * (256 * EPT);

    cnt[tid] = 0;
    __syncthreads();

    int h[EPT], t[EPT], pos[EPT];
#pragma unroll
    for (int it = 0; it < EPT; ++it) {
        int idx = cbase + it * 256 + tid;
        if (idx < E) {
            h[it] = triple[3 * idx];
            t[it] = triple[3 * idx + 2];
            pos[it] = atomicAdd(&cnt[h[it] >> BSHIFT], 1);
        }
    }
    __syncthreads();
    if (tid < nbc && cnt[tid] > 0) base[tid] = atomicAdd(&coarse_cur[tid], cnt[tid]);
    __syncthreads();
#pragma unroll
    for (int it = 0; it < EPT; ++it) {
        int idx = cbase + it * 256 + tid;
        if (idx < E)
            pairs[base[h[it] >> BSHIFT] + pos[it]] = make_uint2((unsigned)h[it], (unsigned)t[it]);
    }
}

// ---------------------------------------------------------------------------
// K3: scan of bucket sizes -> dense CSR bucket bases (single block, nbc<=256)
// ---------------------------------------------------------------------------
__global__ __launch_bounds__(256) void bucket_scan_kernel(
    const int* __restrict__ coarse_cur, int* __restrict__ bstart, int nbc)
{
    __shared__ int s[256];
    int tid = threadIdx.x;
    int sz = (tid < nbc) ? (coarse_cur[tid] - tid * CAP) : 0;
    s[tid] = sz;
    __syncthreads();
#pragma unroll
    for (int off = 1; off < 256; off <<= 1) {
        int v = (tid >= off) ? s[tid - off] : 0;
        __syncthreads();
        s[tid] += v;
        __syncthreads();
    }
    if (tid < nbc) bstart[tid] = s[tid] - sz;
}

// ---------------------------------------------------------------------------
// K4: per-bucket CSR build. One block per coarse bucket: LDS histogram of its
// 512 nodes, LDS scan -> startp, LDS-cursor scatter of t into a local dense
// CSR window.
// ---------------------------------------------------------------------------
__global__ __launch_bounds__(512) void bucket_csr_kernel(
    const uint2* __restrict__ pairs, const int* __restrict__ coarse_cur,
    const int* __restrict__ bstart, int* __restrict__ startp,
    int* __restrict__ edge_t, int N, int E)
{
    __shared__ int cnt[BNODES];
    __shared__ int scn[BNODES];
    __shared__ int cursor[BNODES];
    const int b = blockIdx.x;
    const int tid = threadIdx.x;
    const int plo = b * CAP;
    const int psz = coarse_cur[b] - plo;
    const int obase = bstart[b];

    cnt[tid] = 0;
    __syncthreads();
    for (int j = tid; j < psz; j += BNODES)
        atomicAdd(&cnt[pairs[plo + j].x & (BNODES - 1)], 1);
    __syncthreads();
    scn[tid] = cnt[tid];
    __syncthreads();
#pragma unroll
    for (int off = 1; off < BNODES; off <<= 1) {
        int v = (tid >= off) ? scn[tid - off] : 0;
        __syncthreads();
        scn[tid] += v;
        __syncthreads();
    }
    const int excl = scn[tid] - cnt[tid];
    const int node = b * BNODES + tid;
    if (node < N) startp[node] = obase + excl;
    cursor[tid] = obase + excl;
    __syncthreads();
    for (int j = tid; j < psz; j += BNODES) {
        uint2 p = pairs[plo + j];
        int pos = atomicAdd(&cursor[p.x & (BNODES - 1)], 1);
        edge_t[pos] = (int)p.y;
    }
    if (b == 0 && tid == 0) startp[N] = E;
}

// ---------------------------------------------------------------------------
// K5: per-node softmax aggregation. One wave/node. 8 edge-groups x 8 lanes;
// lane (k = lane>>3) owns dims [16k,16k+16). deg<=64 fast path: scores fully
// in-register; gather restructured into static 32-edge chunks with all 8
// 16B loads/lane issued before any FMA (max MLP). Tail lanes clamp to row 0
// with weight 0 (L1-hot, free).
// ---------------------------------------------------------------------------
__global__ __launch_bounds__(256) void aggregate_kernel(
    const u16* __restrict__ xbf, const float* __restrict__ ssrc,
    const float* __restrict__ sdst, const int* __restrict__ startp,
    const int* __restrict__ edge_t, float* __restrict__ out, int N)
{
    const int wave = threadIdx.x >> 6;
    const int lane = threadIdx.x & 63;
    const int i = blockIdx.x * 4 + wave;
    if (i >= N) return;
    const int lo = startp[i];
    const int hi = startp[i + 1];
    const int deg = hi - lo;
    const float si = ssrc[i];
    const int k = lane >> 3;   // dim-slice 0..7
    const int g = lane & 7;    // edge-group 0..7

    float acc[16];
#pragma unroll
    for (int d = 0; d < 16; d++) acc[d] = 0.f;

    if (deg <= 64) {
        int j = lo + lane;
        bool act = j < hi;
        int t = act ? edge_t[j] : 0;
        float e = act ? si + sdst[t] : -INFINITY;
        e = (e > 0.f) ? e : 0.2f * e;
        float m = e;
#pragma unroll
        for (int off = 32; off; off >>= 1) m = fmaxf(m, __shfl_xor(m, off));
        float p = act ? __expf(e - m) : 0.f;
        float den = p;
#pragma unroll
        for (int off = 32; off; off >>= 1) den += __shfl_xor(den, off);
        float w = (deg > 0) ? p / den : 0.f;

        const u16* xk = xbf + (size_t)k * 16;
#pragma unroll
        for (int c = 0; c < 2; ++c) {
            if (c * 32 < deg) {
                int tt[4]; float ww[4];
                u16x8 v0[4], v1[4];
#pragma unroll
                for (int s = 0; s < 4; ++s) {
                    int ei = c * 32 + s * 8 + g;
                    tt[s] = __shfl(t, ei);     // lanes >= deg hold t=0
                    ww[s] = __shfl(w, ei);     // and w=0 -> contribution 0
                }
#pragma unroll
                for (int s = 0; s < 4; ++s) {
                    const u16x8* src = (const u16x8*)(xk + (size_t)tt[s] * OUT_DIM);
                    v0[s] = src[0];
                    v1[s] = src[1];
                }
#pragma unroll
                for (int s = 0; s < 4; ++s) {
#pragma unroll
                    for (int d = 0; d < 8; d++) {
                        acc[d]     += ww[s] * bf2f(v0[s][d]);
                        acc[8 + d] += ww[s] * bf2f(v1[s][d]);
                    }
                }
            }
        }
    } else {
        float m = -INFINITY;
        for (int j = lo + lane; j < hi; j += 64) {
            int t = edge_t[j];
            float e = si + sdst[t];
            e = (e > 0.f) ? e : 0.2f * e;
            m = fmaxf(m, e);
        }
#pragma unroll
        for (int off = 32; off; off >>= 1) m = fmaxf(m, __shfl_xor(m, off));
        float den = 0.f;
        for (int j = lo + lane; j < hi; j += 64) {
            int t = edge_t[j];
            float e = si + sdst[t];
            e = (e > 0.f) ? e : 0.2f * e;
            den += __expf(e - m);
        }
#pragma unroll
        for (int off = 32; off; off >>= 1) den += __shfl_xor(den, off);
        const float invden = 1.f / den;

        for (int jj = lo; jj < hi; jj += 8) {
            int ei = jj + g;
            if (ei < hi) {
                int tt = edge_t[ei];
                float e = si + sdst[tt];
                e = (e > 0.f) ? e : 0.2f * e;
                float ww = __expf(e - m) * invden;
                const u16x8* src = (const u16x8*)(xbf + (size_t)tt * OUT_DIM + k * 16);
                u16x8 v0 = src[0], v1 = src[1];
#pragma unroll
                for (int d = 0; d < 8; d++) {
                    acc[d]     += ww * bf2f(v0[d]);
                    acc[8 + d] += ww * bf2f(v1[d]);
                }
            }
        }
    }

#pragma unroll
    for (int off = 1; off < 8; off <<= 1) {
#pragma unroll
        for (int d = 0; d < 16; d++) acc[d] += __shfl_xor(acc[d], off);
    }

    if (g == 0) {
        const u16x8* xr = (const u16x8*)(xbf + (size_t)i * OUT_DIM + k * 16);
        u16x8 x0 = xr[0], x1 = xr[1];
        float o[16];
#pragma unroll
        for (int d = 0; d < 8; d++) {
            o[d]     = acc[d]     + bf2f(x0[d]);
            o[8 + d] = acc[8 + d] + bf2f(x1[d]);
        }
#pragma unroll
        for (int d = 0; d < 16; d++) o[d] = (o[d] > 0.f) ? o[d] : __expf(o[d]) - 1.f;
        float* dst = out + (size_t)i * OUT_DIM + k * 16;
#pragma unroll
        for (int u = 0; u < 4; u++)
            *(float4*)(dst + u * 4) = make_float4(o[u*4], o[u*4+1], o[u*4+2], o[u*4+3]);
    }
}

// ---------------------------------------------------------------------------
extern "C" void kernel_launch(void* const* d_in, const int* in_sizes, int n_in,
                              void* d_out, int out_size, void* d_ws, size_t ws_size,
                              hipStream_t stream)
{
    const float* input  = (const float*)d_in[0];
    const float* W      = (const float*)d_in[1];
    const float* a      = (const float*)d_in[2];
    const int*   triple = (const int*)d_in[3];
    const int N = in_sizes[0] / IN_DIM;
    const int E = in_sizes[3] / 3;
    float* out = (float*)d_out;

    const int NBC = (N + BNODES - 1) >> BSHIFT;   // coarse buckets (<=256)

    // workspace layout
    char* p = (char*)d_ws;
    u16* xbf = (u16*)p;                 p += (size_t)N * OUT_DIM * sizeof(u16);
    u16* Wt  = (u16*)p;                 p += (size_t)IN_DIM * OUT_DIM * sizeof(u16);
    float* ssrc = (float*)p;            p += (size_t)N * sizeof(float);
    float* sdst = (float*)p;            p += (size_t)N * sizeof(float);
    int* startp = (int*)p;              p += (size_t)(N + 1) * sizeof(int);
    int* coarse_cur = (int*)p;          p += 256 * sizeof(int);
    int* bstart = (int*)p;              p += 256 * sizeof(int);
    int* edge_t = (int*)p;              p += (size_t)E * sizeof(int);
    p = (char*)(((size_t)p + 15) & ~(size_t)15);
    uint2* pairs = (uint2*)p;           // NBC * CAP * 8 bytes

    const int NCHUNK = (E + 256 * EPT - 1) / (256 * EPT);

    wt_kernel<<<IN_DIM, OUT_DIM, 0, stream>>>(W, Wt, coarse_cur, NBC);
    gemm_xw_kernel<<<(N + BM - 1) / BM, 256, 0, stream>>>(input, Wt, a, xbf, ssrc, sdst, N);
    coarse_scatter_kernel<<<NCHUNK, 256, 0, stream>>>(triple, coarse_cur, pairs, E, NBC);
    bucket_scan_kernel<<<1, 256, 0, stream>>>(coarse_cur, bstart, NBC);
    bucket_csr_kernel<<<NBC, BNODES, 0, stream>>>(pairs, coarse_cur, bstart, startp, edge_t, N, E);
    aggregate_kernel<<<(N + 3) / 4, 256, 0, stream>>>(xbf, ssrc, sdst, startp, edge_t, out, N);
}